// Round 1
// baseline (114.053 us; speedup 1.0000x reference)
//
#include <hip/hip_runtime.h>
#include <math.h>

#define NB 384          // batch size B
#define ND 256          // embedding dim D
#define ND4 (ND/4)
#define TMARGIN 0.3f

// One block per anchor. Block a computes dist[a][:], then mines semi-hard
// negatives per positive, reduces (loss_sum, valid_count) for this anchor.
__global__ __launch_bounds__(NB) void triplet_main(
    const float* __restrict__ emb, const int* __restrict__ labels,
    float* __restrict__ ws_loss, float* __restrict__ ws_cnt)
{
    const int a = blockIdx.x;
    const int t = threadIdx.x;

    __shared__ float4 sa4[ND4];    // anchor embedding (1 KB)
    __shared__ float  sdist[NB];   // dist[a][:]
    __shared__ int    slabel[NB];
    __shared__ float  sredA[512];
    __shared__ float  sredB[512];

    const float4* E4 = (const float4*)emb;

    if (t < ND4) sa4[t] = E4[a * ND4 + t];
    slabel[t] = labels[t];
    __syncthreads();

    // thread t computes dot(e_a, e_t), ||e_t||^2, ||e_a||^2
    float dot = 0.f, sq = 0.f, sqa = 0.f;
    #pragma unroll 8
    for (int k = 0; k < ND4; k++) {
        float4 v = E4[t * ND4 + k];
        float4 u = sa4[k];
        dot += v.x*u.x + v.y*u.y + v.z*u.z + v.w*u.w;
        sq  += v.x*v.x + v.y*v.y + v.z*v.z + v.w*v.w;
        sqa += u.x*u.x + u.y*u.y + u.z*u.z + u.w*u.w;
    }
    sdist[t] = fmaxf(sqa + sq - 2.f * dot, 0.f);
    __syncthreads();

    const int la = slabel[a];

    // d_negmin[a] = min over negatives of dist[a][n]
    sredA[t] = (slabel[t] != la) ? sdist[t] : INFINITY;
    if (t < 512 - NB) sredA[NB + t] = INFINITY;
    __syncthreads();
    for (int s = 256; s > 0; s >>= 1) {
        if (t < s) sredA[t] = fminf(sredA[t], sredA[t + s]);
        __syncthreads();
    }
    const float negmin = sredA[0];
    const bool has_neg = (negmin < INFINITY);
    __syncthreads();   // everyone has read sredA[0] before reuse

    // mining: thread t is positive p=t if same label and not the anchor
    float myloss = 0.f, mycnt = 0.f;
    if (has_neg && slabel[t] == la && t != a) {
        const float dp = sdist[t];
        const float hi = dp + TMARGIN;
        float dsemi = INFINITY;
        for (int n = 0; n < NB; n++) {
            const float dn = sdist[n];
            if (slabel[n] != la && dn > dp && dn < hi) dsemi = fminf(dsemi, dn);
        }
        const float dan = (dsemi < INFINITY) ? dsemi : negmin;
        myloss = fmaxf(dp - dan + TMARGIN, 0.f);
        mycnt  = 1.f;
    }

    // block sum-reduce loss and count
    sredA[t] = myloss;
    sredB[t] = mycnt;
    if (t < 512 - NB) { sredA[NB + t] = 0.f; sredB[NB + t] = 0.f; }
    __syncthreads();
    for (int s = 256; s > 0; s >>= 1) {
        if (t < s) {
            sredA[t] += sredA[t + s];
            sredB[t] += sredB[t + s];
        }
        __syncthreads();
    }
    if (t == 0) {
        ws_loss[a] = sredA[0];
        ws_cnt[a]  = sredB[0];
    }
}

__global__ __launch_bounds__(NB) void triplet_final(
    const float* __restrict__ ws_loss, const float* __restrict__ ws_cnt,
    float* __restrict__ out)
{
    const int t = threadIdx.x;
    __shared__ float sl[512];
    __shared__ float sc[512];
    sl[t] = ws_loss[t];
    sc[t] = ws_cnt[t];
    if (t < 512 - NB) { sl[NB + t] = 0.f; sc[NB + t] = 0.f; }
    __syncthreads();
    for (int s = 256; s > 0; s >>= 1) {
        if (t < s) { sl[t] += sl[t + s]; sc[t] += sc[t + s]; }
        __syncthreads();
    }
    if (t == 0) out[0] = sl[0] / fmaxf(sc[0], 1.f);
}

extern "C" void kernel_launch(void* const* d_in, const int* in_sizes, int n_in,
                              void* d_out, int out_size, void* d_ws, size_t ws_size,
                              hipStream_t stream) {
    const float* emb   = (const float*)d_in[0];   // (384, 256) fp32
    const int* labels  = (const int*)d_in[1];     // (384,) int32
    float* out = (float*)d_out;

    float* ws_loss = (float*)d_ws;
    float* ws_cnt  = ws_loss + NB;

    triplet_main<<<NB, NB, 0, stream>>>(emb, labels, ws_loss, ws_cnt);
    triplet_final<<<1, NB, 0, stream>>>(ws_loss, ws_cnt, out);
}

// Round 2
// 86.905 us; speedup vs baseline: 1.3124x; 1.3124x over previous
//
#include <hip/hip_runtime.h>
#include <math.h>

#define NB 384          // batch size B
#define ND4 64          // D/4 = 256/4
#define NW 6            // waves per block (384 threads)
#define TMARGIN 0.3f

// One block per anchor, 6 waves. Phase 1: each wave-iteration computes one
// full dist row entry via coalesced float4 row load + butterfly reduce.
// Phase 2: negmin + positives list. Phase 3: parallel semi-hard mining,
// one positive per wave, lanes split the 384-row scan.
__global__ __launch_bounds__(NB) void triplet_main(
    const float4* __restrict__ E4, const int* __restrict__ labels,
    float* __restrict__ ws_loss, float* __restrict__ ws_cnt)
{
    const int a = blockIdx.x;
    const int t = threadIdx.x;
    const int w = t >> 6;     // wave id 0..5
    const int l = t & 63;     // lane id

    __shared__ float4 sa4[ND4];    // anchor embedding (1 KB)
    __shared__ float  sdist[NB];   // dist[a][:]
    __shared__ int    slabel[NB];
    __shared__ int    spos[NB];    // positive indices
    __shared__ int    scount;
    __shared__ float  swred[NW];
    __shared__ float  snegmin;

    if (t == 0) scount = 0;
    if (t < ND4) sa4[t] = E4[a * ND4 + t];
    slabel[t] = labels[t];
    __syncthreads();

    // ---- phase 1: dist row. wave w handles rows [64w, 64w+64). ----
    {
        const float4 u = sa4[l];                       // lane-linear, conflict-free
        const float4* p = E4 + (w << 6) * ND4 + l;     // lane l = float4 #l of row
        #pragma unroll 4
        for (int it = 0; it < 64; ++it, p += ND4) {
            float4 v = *p;                             // 64 lanes x 16B = one row, coalesced
            float dx = v.x - u.x, dy = v.y - u.y, dz = v.z - u.z, dw_ = v.w - u.w;
            float d = dx*dx + dy*dy + dz*dz + dw_*dw_; // ||a - e_r||^2 partial
            #pragma unroll
            for (int off = 32; off > 0; off >>= 1)
                d += __shfl_xor(d, off, 64);
            if (l == 0) sdist[(w << 6) + it] = d;
        }
    }
    __syncthreads();

    const int la = slabel[a];

    // ---- phase 2: negmin over row + collect positives ----
    float nm = (slabel[t] != la) ? sdist[t] : INFINITY;
    #pragma unroll
    for (int off = 32; off > 0; off >>= 1)
        nm = fminf(nm, __shfl_xor(nm, off, 64));
    if (l == 0) swred[w] = nm;
    if (slabel[t] == la && t != a) {
        int idx = atomicAdd(&scount, 1);
        spos[idx] = t;
    }
    __syncthreads();
    if (t == 0) {
        float m = swred[0];
        #pragma unroll
        for (int i = 1; i < NW; ++i) m = fminf(m, swred[i]);
        snegmin = m;
    }
    __syncthreads();

    const float negmin = snegmin;
    const int   P      = scount;
    const bool  has_neg = (negmin < INFINITY);

    // ---- phase 3: semi-hard mining, one positive per wave ----
    float lsum = 0.f;
    if (has_neg) {
        for (int pi = w; pi < P; pi += NW) {
            const int   p  = spos[pi];
            const float dp = sdist[p];
            const float hi = dp + TMARGIN;
            float m = INFINITY;
            #pragma unroll
            for (int i = 0; i < NB / 64; ++i) {
                const int   n  = (i << 6) + l;
                const float dn = sdist[n];
                if ((slabel[n] != la) && (dn > dp) && (dn < hi))
                    m = fminf(m, dn);
            }
            #pragma unroll
            for (int off = 32; off > 0; off >>= 1)
                m = fminf(m, __shfl_xor(m, off, 64));
            if (l == 0) {
                const float dan = (m < INFINITY) ? m : negmin;
                lsum += fmaxf(dp - dan + TMARGIN, 0.f);
            }
        }
    }

    // ---- reduce loss across waves; count = P when has_neg ----
    __syncthreads();               // protect swred reuse
    if (l == 0) swred[w] = lsum;
    __syncthreads();
    if (t == 0) {
        float s = 0.f;
        #pragma unroll
        for (int i = 0; i < NW; ++i) s += swred[i];
        ws_loss[a] = s;
        ws_cnt[a]  = has_neg ? (float)P : 0.f;
    }
}

__global__ __launch_bounds__(NB) void triplet_final(
    const float* __restrict__ ws_loss, const float* __restrict__ ws_cnt,
    float* __restrict__ out)
{
    const int t = threadIdx.x;
    __shared__ float sl[512];
    __shared__ float sc[512];
    sl[t] = ws_loss[t];
    sc[t] = ws_cnt[t];
    if (t < 512 - NB) { sl[NB + t] = 0.f; sc[NB + t] = 0.f; }
    __syncthreads();
    for (int s = 256; s > 0; s >>= 1) {
        if (t < s) { sl[t] += sl[t + s]; sc[t] += sc[t + s]; }
        __syncthreads();
    }
    if (t == 0) out[0] = sl[0] / fmaxf(sc[0], 1.f);
}

extern "C" void kernel_launch(void* const* d_in, const int* in_sizes, int n_in,
                              void* d_out, int out_size, void* d_ws, size_t ws_size,
                              hipStream_t stream) {
    const float4* emb  = (const float4*)d_in[0];   // (384, 256) fp32
    const int* labels  = (const int*)d_in[1];      // (384,) int32
    float* out = (float*)d_out;

    float* ws_loss = (float*)d_ws;
    float* ws_cnt  = ws_loss + NB;

    triplet_main<<<NB, NB, 0, stream>>>(emb, labels, ws_loss, ws_cnt);
    triplet_final<<<1, NB, 0, stream>>>(ws_loss, ws_cnt, out);
}

// Round 3
// 77.823 us; speedup vs baseline: 1.4655x; 1.1167x over previous
//
#include <hip/hip_runtime.h>
#include <math.h>

#define NB 384          // batch size B
#define ND4 64          // D/4 = 256/4
#define NW 6            // waves per block (384 threads)
#define TMARGIN 0.3f

// One block per anchor (384 blocks x 384 threads).
// Phase 1: dist row via 8-lanes-per-row coalesced float4 loads (3 shuffles/8 rows).
// Phase 2: negmin + positives list. Phase 3: semi-hard mining, one positive/wave.
// Finalize: atomic partials + ticket; last block writes the mean loss.
__global__ __launch_bounds__(NB) void triplet_main(
    const float4* __restrict__ E4, const int* __restrict__ labels,
    float* __restrict__ gsum, float* __restrict__ gcnt,
    unsigned int* __restrict__ gticket, float* __restrict__ out)
{
    const int a = blockIdx.x;
    const int t = threadIdx.x;
    const int w = t >> 6;     // wave id 0..5
    const int l = t & 63;     // lane id
    const int s = l & 7;      // sub-lane within 8-lane row group
    const int g = l >> 3;     // row group 0..7

    __shared__ float4 sa4[ND4];    // anchor embedding (1 KB)
    __shared__ float  sdist[NB];   // dist[a][:]
    __shared__ int    slabel[NB];
    __shared__ int    spos[NB];    // positive indices
    __shared__ int    scount;
    __shared__ float  swred[NW];
    __shared__ float  snegmin;

    if (t == 0) scount = 0;
    if (t < ND4) sa4[t] = E4[a * ND4 + t];
    slabel[t] = labels[t];
    __syncthreads();

    // preload anchor float4s this sub-lane needs: sa4[s + 8j] (broadcast reads)
    float4 u[8];
    #pragma unroll
    for (int j = 0; j < 8; ++j) u[j] = sa4[s + (j << 3)];

    // ---- phase 1: wave w computes rows [64w, 64w+64), 8 rows per iter ----
    #pragma unroll
    for (int i = 0; i < 8; ++i) {
        const int row = (w << 6) + (i << 3) + g;
        const float4* __restrict__ p = E4 + row * ND4 + s;
        float d = 0.f;
        #pragma unroll
        for (int j = 0; j < 8; ++j) {
            float4 v = p[j << 3];                      // lanes 0-7 cover 128B of row
            float dx = v.x - u[j].x, dy = v.y - u[j].y;
            float dz = v.z - u[j].z, dq = v.w - u[j].w;
            d += dx*dx + dy*dy + dz*dz + dq*dq;
        }
        d += __shfl_xor(d, 1, 64);                     // reduce within 8-lane group
        d += __shfl_xor(d, 2, 64);
        d += __shfl_xor(d, 4, 64);
        if (s == 0) sdist[row] = d;
    }
    __syncthreads();

    const int la = slabel[a];

    // ---- phase 2: negmin over row + collect positives ----
    float nm = (slabel[t] != la) ? sdist[t] : INFINITY;
    #pragma unroll
    for (int off = 32; off > 0; off >>= 1)
        nm = fminf(nm, __shfl_xor(nm, off, 64));
    if (l == 0) swred[w] = nm;
    if (slabel[t] == la && t != a) {
        int idx = atomicAdd(&scount, 1);
        spos[idx] = t;
    }
    __syncthreads();
    if (t == 0) {
        float m = swred[0];
        #pragma unroll
        for (int i = 1; i < NW; ++i) m = fminf(m, swred[i]);
        snegmin = m;
    }
    __syncthreads();

    const float negmin  = snegmin;
    const int   P       = scount;
    const bool  has_neg = (negmin < INFINITY);

    // ---- phase 3: semi-hard mining, one positive per wave ----
    float lsum = 0.f;
    if (has_neg) {
        for (int pi = w; pi < P; pi += NW) {
            const int   p  = spos[pi];
            const float dp = sdist[p];
            const float hi = dp + TMARGIN;
            float m = INFINITY;
            #pragma unroll
            for (int i = 0; i < NB / 64; ++i) {
                const int   n  = (i << 6) + l;
                const float dn = sdist[n];
                if ((slabel[n] != la) && (dn > dp) && (dn < hi))
                    m = fminf(m, dn);
            }
            #pragma unroll
            for (int off = 32; off > 0; off >>= 1)
                m = fminf(m, __shfl_xor(m, off, 64));
            if (l == 0) {
                const float dan = (m < INFINITY) ? m : negmin;
                lsum += fmaxf(dp - dan + TMARGIN, 0.f);
            }
        }
    }

    // ---- block reduce + global atomic accumulate + last-block finalize ----
    __syncthreads();               // protect swred reuse
    if (l == 0) swred[w] = lsum;
    __syncthreads();
    if (t == 0) {
        float ssum = swred[0];
        #pragma unroll
        for (int i = 1; i < NW; ++i) ssum += swred[i];
        const float scnt = has_neg ? (float)P : 0.f;
        atomicAdd(gsum, ssum);
        atomicAdd(gcnt, scnt);
        __threadfence();                               // device-scope visibility
        const unsigned int tk = atomicAdd(gticket, 1u);
        if (tk == NB - 1) {                            // last block to arrive
            const float S = atomicAdd(gsum, 0.f);      // coherent read of total
            const float C = atomicAdd(gcnt, 0.f);
            out[0] = S / fmaxf(C, 1.f);
        }
    }
}

extern "C" void kernel_launch(void* const* d_in, const int* in_sizes, int n_in,
                              void* d_out, int out_size, void* d_ws, size_t ws_size,
                              hipStream_t stream) {
    const float4* emb  = (const float4*)d_in[0];   // (384, 256) fp32
    const int* labels  = (const int*)d_in[1];      // (384,) int32
    float* out = (float*)d_out;

    float* gsum = (float*)d_ws;                    // ws[0]
    float* gcnt = gsum + 1;                        // ws[1]
    unsigned int* gticket = (unsigned int*)d_ws + 2;

    // zero accumulators + ticket (ws is re-poisoned to 0xAA before every call)
    hipMemsetAsync(d_ws, 0, 16, stream);
    triplet_main<<<NB, NB, 0, stream>>>(emb, labels, gsum, gcnt, gticket, out);
}